// Round 5
// baseline (335.804 us; speedup 1.0000x reference)
//
#include <hip/hip_runtime.h>
#include <hip/hip_bf16.h>
#include <stdint.h>

#define T_SZ 2048
#define B_SZ 64
#define H_SZ 256
#define I_SZ 256
#define M_SZ (B_SZ * T_SZ)          // 131072
#define TBH  (T_SZ * B_SZ * H_SZ)   // 33554432

typedef float f32x4 __attribute__((ext_vector_type(4)));
typedef short s16x8 __attribute__((ext_vector_type(8)));

// RTNE fp32 -> bf16 pair packed into one u32 (low = a, high = b)
__device__ __forceinline__ unsigned pack_bf16(float a, float b) {
    unsigned ua = __float_as_uint(a);
    unsigned ub = __float_as_uint(b);
    ua += 0x7fffu + ((ua >> 16) & 1u);
    ub += 0x7fffu + ((ub >> 16) & 1u);
    return (ua >> 16) | (ub & 0xffff0000u);
}

// ---------------------------------------------------------------------------
// prep: gb[b,h] = sum_j h0[b,j]*W_fh[h,j] + b_fi[h] + b_fh[h]
//       + convert W_fi (fp32 HxI) -> bf16 into Wb
// ---------------------------------------------------------------------------
__global__ void prep_kernel(const float* __restrict__ h0,
                            const float* __restrict__ W_fi,
                            const float* __restrict__ b_fi,
                            const float* __restrict__ W_fh,
                            const float* __restrict__ b_fh,
                            unsigned short* __restrict__ Wb,
                            float* __restrict__ gb) {
    __shared__ float h0s[H_SZ];
    const int b = blockIdx.x;
    const int h = threadIdx.x;
    h0s[h] = h0[b * H_SZ + h];
    __syncthreads();
    const float4* w4 = (const float4*)(W_fh + (size_t)h * H_SZ);
    float acc = 0.f;
#pragma unroll 8
    for (int j = 0; j < H_SZ / 4; ++j) {
        float4 w = w4[j];
        acc = fmaf(w.x, h0s[4 * j + 0], acc);
        acc = fmaf(w.y, h0s[4 * j + 1], acc);
        acc = fmaf(w.z, h0s[4 * j + 2], acc);
        acc = fmaf(w.w, h0s[4 * j + 3], acc);
    }
    gb[b * H_SZ + h] = acc + b_fi[h] + b_fh[h];

    const int e = (b * 256 + h) * 4;
    float4 wv = *(const float4*)(W_fi + e);
    uint2 pk;
    pk.x = pack_bf16(wv.x, wv.y);
    pk.y = pack_bf16(wv.z, wv.w);
    *(uint2*)(Wb + e) = pk;
}

// ---------------------------------------------------------------------------
// main: gx = x @ W_fi^T, M=131072, N=256, K=256, fused LSTM epilogue.
// Block 64M x 256N, 512 thr = 8 waves of 32x64 (acc 2x4). BK=64, LDS rows
// 128 B, XOR-swizzle ((row&7)<<4 bytes) on both write & read sides (T2,
// rule #21: linear phys write pos + pre-swizzled GLOBAL source). Double-
// buffered LDS (2 x 40 KB -> 2 blocks/CU); ONE barrier per kt (4 total):
//   frag reads(buf c) -> issue loads kt+2 -> ds_write kt+1 -> lgkmcnt(0)
//   -> s_barrier -> MFMA (regs only).
// Counted vmcnt at the ds_write (kt+2 loads stay in flight across barrier).
// ---------------------------------------------------------------------------
__global__ __launch_bounds__(512, 4) void lstm_main(
    const float* __restrict__ x,
    const unsigned short* __restrict__ Wb,
    const float* __restrict__ gb,
    const float* __restrict__ c0,
    float* __restrict__ out) {
    // per buf (20480 elems): A = 64 rows x 64 bf16 (elems [0,4096)),
    //                        B = 256 rows x 64 bf16 (elems [4096,20480))
    __shared__ __align__(16) unsigned short Ls[2 * 20480];   // 80 KB

    const int tid  = threadIdx.x;
    const int lane = tid & 63;
    const int wid  = tid >> 6;
    const int m0 = blockIdx.x * 64;
    const int wm = (wid & 1) * 32;
    const int wn = (wid >> 1) * 64;
    const int fr = lane & 15;
    const int fq = lane >> 4;

    // ---- A staging: thread -> (row = tid>>3, phys 16B-pos = tid&7) ----
    const int arow = tid >> 3, aseg = tid & 7;
    const int axm = (arow & 7) << 3;                    // swizzle XOR (elems)
    const float* aGp = x + (size_t)(m0 + arow) * I_SZ + ((aseg * 8) ^ axm);
    const int aLo = arow * 64 + aseg * 8;               // linear phys (conflict-free)

    // ---- B staging: w=0..3: row = (tid>>3)+w*64, phys pos = tid&7 ----
    const int brow = tid >> 3, bpos = tid & 7;
    const int bxm = (brow & 7) << 3;                    // row+64k keeps row&7
    const int bgo = brow * 256 + ((bpos * 8) ^ bxm);    // global elem offset
    const int bLo = 4096 + brow * 64 + bpos * 8;        // + w*4096 elems

    // ---- fragment read offsets (swizzled), ks in {0,1} ----
    const int fxm = (fr & 7) << 3;
    int aro[2], bro[2];
#pragma unroll
    for (int ks = 0; ks < 2; ++ks) {
        const int c = (ks * 32 + fq * 8) ^ fxm;
        aro[ks] = (wm + fr) * 64 + c;                   // + mi*1024 elems
        bro[ks] = 4096 + (wn + fr) * 64 + c;            // + ni*1024 elems
    }

    float4 sa[2][2];
    uint4  sb[2][4];

    auto LOAD = [&](int s, int kt) {
        sa[s][0] = *(const float4*)(aGp + kt * 64);
        sa[s][1] = *(const float4*)(aGp + kt * 64 + 4);
#pragma unroll
        for (int w = 0; w < 4; ++w)
            sb[s][w] = *(const uint4*)(Wb + bgo + w * 64 * 256 + kt * 64);
    };
    auto WRITE = [&](int s, int buf) {
        unsigned short* L = Ls + buf * 20480;
        uint4 ap;
        ap.x = pack_bf16(sa[s][0].x, sa[s][0].y);
        ap.y = pack_bf16(sa[s][0].z, sa[s][0].w);
        ap.z = pack_bf16(sa[s][1].x, sa[s][1].y);
        ap.w = pack_bf16(sa[s][1].z, sa[s][1].w);
        *(uint4*)(L + aLo) = ap;
#pragma unroll
        for (int w = 0; w < 4; ++w)
            *(uint4*)(L + bLo + w * 4096) = sb[s][w];
    };

    f32x4 acc[2][4];
#pragma unroll
    for (int mi = 0; mi < 2; ++mi)
#pragma unroll
        for (int ni = 0; ni < 4; ++ni)
            acc[mi][ni] = (f32x4){0.f, 0.f, 0.f, 0.f};

    // prologue: tile0 -> buf0; tile1 in flight
    LOAD(0, 0);
    WRITE(0, 0);
    LOAD(1, 1);
    asm volatile("s_waitcnt lgkmcnt(0)" ::: "memory");
    __builtin_amdgcn_sched_barrier(0);
    __builtin_amdgcn_s_barrier();
    __builtin_amdgcn_sched_barrier(0);

#pragma unroll
    for (int kt = 0; kt < 4; ++kt) {
        const unsigned short* L = Ls + (kt & 1) * 20480;
        s16x8 af[2][2], bf[4][2];
#pragma unroll
        for (int ks = 0; ks < 2; ++ks) {
#pragma unroll
            for (int mi = 0; mi < 2; ++mi)
                af[mi][ks] = *(const s16x8*)(L + aro[ks] + mi * 1024);
#pragma unroll
            for (int ni = 0; ni < 4; ++ni)
                bf[ni][ks] = *(const s16x8*)(L + bro[ks] + ni * 1024);
        }
        if (kt < 2) LOAD(kt & 1, kt + 2);          // issue first -> counted vmcnt
        if (kt < 3) WRITE((kt + 1) & 1, (kt & 1) ^ 1);
        asm volatile("s_waitcnt lgkmcnt(0)" ::: "memory");
        __builtin_amdgcn_sched_barrier(0);
        if (kt < 3) __builtin_amdgcn_s_barrier();
        __builtin_amdgcn_sched_barrier(0);
        __builtin_amdgcn_s_setprio(1);
#pragma unroll
        for (int ks = 0; ks < 2; ++ks)
#pragma unroll
            for (int mi = 0; mi < 2; ++mi)
#pragma unroll
                for (int ni = 0; ni < 4; ++ni)
                    acc[mi][ni] = __builtin_amdgcn_mfma_f32_16x16x32_bf16(
                        af[mi][ks], bf[ni][ks], acc[mi][ni], 0, 0, 0);
        __builtin_amdgcn_s_setprio(0);
    }

    // Epilogue: C/D layout col = lane&15, row = (lane>>4)*4 + reg
    const int bb = m0 >> 11;            // 64 | 2048 -> constant per block
    const int coln = wn + fr;
    float gbv[4], c0v[4];
#pragma unroll
    for (int ni = 0; ni < 4; ++ni) {
        gbv[ni] = gb[bb * H_SZ + coln + ni * 16];
        c0v[ni] = c0[bb * H_SZ + coln + ni * 16];
    }
#pragma unroll
    for (int mi = 0; mi < 2; ++mi) {
#pragma unroll
        for (int r = 0; r < 4; ++r) {
            const int Mg = m0 + wm + mi * 16 + fq * 4 + r;
            const int tt = Mg & (T_SZ - 1);
            const int obase = tt * (B_SZ * H_SZ) + bb * H_SZ;
            const bool last = (tt == T_SZ - 1);
#pragma unroll
            for (int ni = 0; ni < 4; ++ni) {
                const int h = coln + ni * 16;
                float g = acc[mi][ni][r] + gbv[ni];
                float gc = fmaxf(-15.f, g);                       // NaN guard only
                float e = __expf(-gc);
                float s = __builtin_amdgcn_rcpf(1.f + e);         // sigmoid(g)
                float e2 = e * e;
                float m = (1.f - e2) * __builtin_amdgcn_rcpf(1.f + e2);  // tanh(g)
                float cv = s * (c0v[ni] + m);                     // |cv| <= |c0|+1
                float ec = __expf(-2.f * cv);
                float th = (1.f - ec) * __builtin_amdgcn_rcpf(1.f + ec); // tanh(c)
                float hv = s * th;
                out[obase + h] = hv;
                if (last) {
                    out[TBH + bb * H_SZ + h] = hv;                 // h_last
                    out[TBH + B_SZ * H_SZ + bb * H_SZ + h] = cv;   // c_last
                }
            }
        }
    }
}

extern "C" void kernel_launch(void* const* d_in, const int* in_sizes, int n_in,
                              void* d_out, int out_size, void* d_ws, size_t ws_size,
                              hipStream_t stream) {
    const float* x    = (const float*)d_in[0];
    const float* h0   = (const float*)d_in[1];
    const float* c0   = (const float*)d_in[2];
    const float* W_fi = (const float*)d_in[3];
    const float* b_fi = (const float*)d_in[4];
    const float* W_fh = (const float*)d_in[5];
    const float* b_fh = (const float*)d_in[6];
    float* out = (float*)d_out;

    unsigned short* Wb = (unsigned short*)d_ws;               // 128 KB
    float* gb = (float*)((char*)d_ws + 131072);               // 64 KB

    hipLaunchKernelGGL(prep_kernel, dim3(B_SZ), dim3(H_SZ), 0, stream,
                       h0, W_fi, b_fi, W_fh, b_fh, Wb, gb);
    hipLaunchKernelGGL(lstm_main, dim3(M_SZ / 64), dim3(512), 0, stream,
                       x, Wb, gb, c0, out);
}

// Round 6
// 278.334 us; speedup vs baseline: 1.2065x; 1.2065x over previous
//
#include <hip/hip_runtime.h>
#include <hip/hip_bf16.h>
#include <stdint.h>

#define T_SZ 2048
#define B_SZ 64
#define H_SZ 256
#define I_SZ 256
#define M_SZ (B_SZ * T_SZ)          // 131072
#define TBH  (T_SZ * B_SZ * H_SZ)   // 33554432

typedef float f32x4 __attribute__((ext_vector_type(4)));
typedef short s16x8 __attribute__((ext_vector_type(8)));

// RTNE fp32 -> bf16 pair packed into one u32 (low = a, high = b)
__device__ __forceinline__ unsigned pack_bf16(float a, float b) {
    unsigned ua = __float_as_uint(a);
    unsigned ub = __float_as_uint(b);
    ua += 0x7fffu + ((ua >> 16) & 1u);
    ub += 0x7fffu + ((ub >> 16) & 1u);
    return (ua >> 16) | (ub & 0xffff0000u);
}

// ---------------------------------------------------------------------------
// prep: gb[b,h] = sum_j h0[b,j]*W_fh[h,j] + b_fi[h] + b_fh[h]
//       + convert W_fi (fp32 HxI) -> bf16 into Wb
// ---------------------------------------------------------------------------
__global__ void prep_kernel(const float* __restrict__ h0,
                            const float* __restrict__ W_fi,
                            const float* __restrict__ b_fi,
                            const float* __restrict__ W_fh,
                            const float* __restrict__ b_fh,
                            unsigned short* __restrict__ Wb,
                            float* __restrict__ gb) {
    __shared__ float h0s[H_SZ];
    const int b = blockIdx.x;
    const int h = threadIdx.x;
    h0s[h] = h0[b * H_SZ + h];
    __syncthreads();
    const float4* w4 = (const float4*)(W_fh + (size_t)h * H_SZ);
    float acc = 0.f;
#pragma unroll 8
    for (int j = 0; j < H_SZ / 4; ++j) {
        float4 w = w4[j];
        acc = fmaf(w.x, h0s[4 * j + 0], acc);
        acc = fmaf(w.y, h0s[4 * j + 1], acc);
        acc = fmaf(w.z, h0s[4 * j + 2], acc);
        acc = fmaf(w.w, h0s[4 * j + 3], acc);
    }
    gb[b * H_SZ + h] = acc + b_fi[h] + b_fh[h];

    const int e = (b * 256 + h) * 4;
    float4 wv = *(const float4*)(W_fi + e);
    uint2 pk;
    pk.x = pack_bf16(wv.x, wv.y);
    pk.y = pack_bf16(wv.z, wv.w);
    *(uint2*)(Wb + e) = pk;
}

// ---------------------------------------------------------------------------
// main: gx = x @ W_fi^T, M=131072, N=256, K=256, fused LSTM epilogue.
// Block 64M x 256N, 512 thr = 8 waves of 32x64 (acc 2x4 = 32 regs).
// BK=32, double-buffered LDS (2 x 20 KB = 40 KB), ONE barrier per kt:
//   iter kt: ds_read frags(buf kt&1) -> issue G(kt+2) -> ds_write tile kt+1
//   (buf other; counted vmcnt on the 2-iter-old loads) -> lgkmcnt(0)
//   -> s_barrier -> MFMA x16 (regs only).
// Swizzle (64 B rows, 4 x 16 B granules): phys granule g holds logical
// granule g ^ ((row>>1)&3) -- bijective per 8-row stripe; writes are
// phys-linear (conflict-free), reads XOR the same mask (frag row bits 1-2
// == fr bits 1-2 for every mi/ni since offsets are multiples of 16).
// launch_bounds(512,2): 2nd arg is min BLOCKS/CU for hipcc -> 128-reg cap
// (round-5 lesson: (512,4) capped at 64 regs -> 260 MB of scratch spill).
// ---------------------------------------------------------------------------
__global__ __launch_bounds__(512, 2) void lstm_main(
    const float* __restrict__ x,
    const unsigned short* __restrict__ Wb,
    const float* __restrict__ gb,
    const float* __restrict__ c0,
    float* __restrict__ out) {
    // per buf (10240 elems): A = 64x32 bf16 [0,2048), B = 256x32 [2048,10240)
    __shared__ __align__(16) unsigned short Ls[2 * 10240];   // 40 KB

    const int tid  = threadIdx.x;
    const int lane = tid & 63;
    const int wid  = tid >> 6;
    const int m0 = blockIdx.x * 64;
    const int wm = (wid & 1) * 32;
    const int wn = (wid >> 1) * 64;
    const int fr = lane & 15;
    const int fq = lane >> 4;

    // ---- A staging: row = tid>>3, 8 B sub-seg = tid&7; phys-linear dest,
    //      pre-swizzled global source ----
    const int arow = tid >> 3, aseg = tid & 7;
    const int ag = aseg >> 1, asub = aseg & 1;
    const int axm = (arow >> 1) & 3;
    const float* aG = x + (size_t)(m0 + arow) * I_SZ + ((ag ^ axm) * 8 + asub * 4);
    const int aLo = arow * 32 + aseg * 4;                 // elems

    // ---- B staging: slots tid, tid+512; row = slot>>2, granule = slot&3 ----
    int bgo[2], bLo[2];
#pragma unroll
    for (int w = 0; w < 2; ++w) {
        const int slot = w * 512 + tid;
        const int row = slot >> 2, g = slot & 3;
        const int xm = (row >> 1) & 3;
        bgo[w] = row * 256 + ((g ^ xm) * 8);              // global elem off
        bLo[w] = 2048 + row * 32 + g * 8;                 // phys-linear dest
    }

    // ---- fragment read offsets (swizzled) ----
    const int fxm = (fr >> 1) & 3;
    const int fcol = (fq ^ fxm) * 8;
    const int afo = (wm + fr) * 32 + fcol;                // + mi*512
    const int bfo = 2048 + (wn + fr) * 32 + fcol;         // + ni*512

    f32x4 acc[2][4];
#pragma unroll
    for (int mi = 0; mi < 2; ++mi)
#pragma unroll
        for (int ni = 0; ni < 4; ++ni)
            acc[mi][ni] = (f32x4){0.f, 0.f, 0.f, 0.f};

    float4 sa[2];
    uint4  sb[2][2];

    // prologue: issue tiles 0,1; write tile0 -> buf0 (counted vmcnt: 3 newer)
    sa[0]    = *(const float4*)(aG);
    sb[0][0] = *(const uint4*)(Wb + bgo[0]);
    sb[0][1] = *(const uint4*)(Wb + bgo[1]);
    sa[1]    = *(const float4*)(aG + 32);
    sb[1][0] = *(const uint4*)(Wb + bgo[0] + 32);
    sb[1][1] = *(const uint4*)(Wb + bgo[1] + 32);
    {
        uint2 ap;
        ap.x = pack_bf16(sa[0].x, sa[0].y);
        ap.y = pack_bf16(sa[0].z, sa[0].w);
        *(uint2*)(Ls + aLo) = ap;
        *(uint4*)(Ls + bLo[0]) = sb[0][0];
        *(uint4*)(Ls + bLo[1]) = sb[0][1];
    }
    asm volatile("s_waitcnt lgkmcnt(0)" ::: "memory");
    __builtin_amdgcn_sched_barrier(0);
    __builtin_amdgcn_s_barrier();
    __builtin_amdgcn_sched_barrier(0);

#pragma unroll
    for (int kt = 0; kt < 8; ++kt) {
        const unsigned short* L = Ls + (kt & 1) * 10240;
        // 1. fragment ds_reads from current buffer
        s16x8 af[2], bf[4];
#pragma unroll
        for (int mi = 0; mi < 2; ++mi)
            af[mi] = *(const s16x8*)(L + afo + mi * 512);
#pragma unroll
        for (int ni = 0; ni < 4; ++ni)
            bf[ni] = *(const s16x8*)(L + bfo + ni * 512);
        // 2. issue global loads for tile kt+2 into the set just freed
        if (kt < 6) {
            const int s = kt & 1, kof = (kt + 2) * 32;
            sa[s]    = *(const float4*)(aG + kof);
            sb[s][0] = *(const uint4*)(Wb + bgo[0] + kof);
            sb[s][1] = *(const uint4*)(Wb + bgo[1] + kof);
        }
        // 3. write tile kt+1 (loaded 2 iters ago; compiler emits counted vmcnt)
        if (kt < 7) {
            const int s = (kt + 1) & 1;
            unsigned short* Lw = Ls + (((kt + 1) & 1)) * 10240;
            uint2 ap;
            ap.x = pack_bf16(sa[s].x, sa[s].y);
            ap.y = pack_bf16(sa[s].z, sa[s].w);
            *(uint2*)(Lw + aLo) = ap;
            *(uint4*)(Lw + bLo[0]) = sb[s][0];
            *(uint4*)(Lw + bLo[1]) = sb[s][1];
        }
        // 4. one barrier: reads(cur) + writes(other) both done; vmcnt stays counted
        asm volatile("s_waitcnt lgkmcnt(0)" ::: "memory");
        __builtin_amdgcn_sched_barrier(0);
        if (kt < 7) __builtin_amdgcn_s_barrier();
        __builtin_amdgcn_sched_barrier(0);
        // 5. MFMA from registers
        __builtin_amdgcn_s_setprio(1);
#pragma unroll
        for (int mi = 0; mi < 2; ++mi)
#pragma unroll
            for (int ni = 0; ni < 4; ++ni)
                acc[mi][ni] = __builtin_amdgcn_mfma_f32_16x16x32_bf16(
                    af[mi], bf[ni], acc[mi][ni], 0, 0, 0);
        __builtin_amdgcn_s_setprio(0);
    }

    // Epilogue: C/D layout col = lane&15, row = (lane>>4)*4 + reg
    const int bb = m0 >> 11;            // 64 | 2048 -> constant per block
    const int coln = wn + fr;
    float gbv[4], c0v[4];
#pragma unroll
    for (int ni = 0; ni < 4; ++ni) {
        gbv[ni] = gb[bb * H_SZ + coln + ni * 16];
        c0v[ni] = c0[bb * H_SZ + coln + ni * 16];
    }
#pragma unroll
    for (int mi = 0; mi < 2; ++mi) {
#pragma unroll
        for (int r = 0; r < 4; ++r) {
            const int Mg = m0 + wm + mi * 16 + fq * 4 + r;
            const int tt = Mg & (T_SZ - 1);
            const int obase = tt * (B_SZ * H_SZ) + bb * H_SZ;
            const bool last = (tt == T_SZ - 1);
#pragma unroll
            for (int ni = 0; ni < 4; ++ni) {
                const int h = coln + ni * 16;
                float g = acc[mi][ni][r] + gbv[ni];
                float gc = fmaxf(-15.f, g);                       // NaN guard only
                float e = __expf(-gc);
                float s = __builtin_amdgcn_rcpf(1.f + e);         // sigmoid(g)
                float e2 = e * e;
                float m = (1.f - e2) * __builtin_amdgcn_rcpf(1.f + e2);  // tanh(g)
                float cv = s * (c0v[ni] + m);                     // |cv| <= |c0|+1
                float ec = __expf(-2.f * cv);
                float th = (1.f - ec) * __builtin_amdgcn_rcpf(1.f + ec); // tanh(c)
                float hv = s * th;
                out[obase + h] = hv;
                if (last) {
                    out[TBH + bb * H_SZ + h] = hv;                 // h_last
                    out[TBH + B_SZ * H_SZ + bb * H_SZ + h] = cv;   // c_last
                }
            }
        }
    }
}

extern "C" void kernel_launch(void* const* d_in, const int* in_sizes, int n_in,
                              void* d_out, int out_size, void* d_ws, size_t ws_size,
                              hipStream_t stream) {
    const float* x    = (const float*)d_in[0];
    const float* h0   = (const float*)d_in[1];
    const float* c0   = (const float*)d_in[2];
    const float* W_fi = (const float*)d_in[3];
    const float* b_fi = (const float*)d_in[4];
    const float* W_fh = (const float*)d_in[5];
    const float* b_fh = (const float*)d_in[6];
    float* out = (float*)d_out;

    unsigned short* Wb = (unsigned short*)d_ws;               // 128 KB
    float* gb = (float*)((char*)d_ws + 131072);               // 64 KB

    hipLaunchKernelGGL(prep_kernel, dim3(B_SZ), dim3(H_SZ), 0, stream,
                       h0, W_fi, b_fi, W_fh, b_fh, Wb, gb);
    hipLaunchKernelGGL(lstm_main, dim3(M_SZ / 64), dim3(512), 0, stream,
                       x, Wb, gb, c0, out);
}

// Round 7
// 274.171 us; speedup vs baseline: 1.2248x; 1.0152x over previous
//
#include <hip/hip_runtime.h>
#include <hip/hip_bf16.h>
#include <stdint.h>

#define T_SZ 2048
#define B_SZ 64
#define H_SZ 256
#define I_SZ 256
#define M_SZ (B_SZ * T_SZ)          // 131072
#define TBH  (T_SZ * B_SZ * H_SZ)   // 33554432

typedef float f32x4 __attribute__((ext_vector_type(4)));
typedef short s16x8 __attribute__((ext_vector_type(8)));

// RTNE fp32 -> bf16 pair packed into one u32 (low = a, high = b)
__device__ __forceinline__ unsigned pack_bf16(float a, float b) {
    unsigned ua = __float_as_uint(a);
    unsigned ub = __float_as_uint(b);
    ua += 0x7fffu + ((ua >> 16) & 1u);
    ub += 0x7fffu + ((ub >> 16) & 1u);
    return (ua >> 16) | (ub & 0xffff0000u);
}

// ---------------------------------------------------------------------------
// Single fused kernel. Grid = 256 blocks (1 per CU) x 512 threads (8 waves,
// 2M x 4N, wave tile 32M x 64N). Each block owns 512 M-rows (8 chunks of 64).
//
// LDS (160 KB exactly):
//   Bs: full W as bf16, 256 rows x 256 k (128 KB), loaded ONCE per block.
//   As: one 64-row x 256-k bf16 chunk (32 KB), restaged per chunk.
// Both swizzled: 16B granule g of row r stored at g ^ (r&7)  ->  frag
// ds_read_b128 is 2-way (free); K-loop has NO barriers, NO global loads.
// Barriers: 2 per chunk (As reuse) + prologue. prep_kernel is fused:
// gb computed cooperatively per block; W_fi converted during B staging.
// A staging: one wave stages one full 1KB x-row per instruction (perfectly
// coalesced float4), converts, ds_write_b64; chunk c+1 loads are issued
// before chunk c's K-loop -> a whole chunk of compute hides the latency.
// ---------------------------------------------------------------------------
__global__ __launch_bounds__(512, 1) void lstm_fused(
    const float* __restrict__ x,
    const float* __restrict__ h0,
    const float* __restrict__ c0,
    const float* __restrict__ W_fi,
    const float* __restrict__ b_fi,
    const float* __restrict__ W_fh,
    const float* __restrict__ b_fh,
    float* __restrict__ out) {
    __shared__ __align__(16) unsigned char smem[163840];
    unsigned short* Bs = (unsigned short*)smem;             // 128 KB
    unsigned short* As = (unsigned short*)(smem + 131072);  // 32 KB
    float* h0s = (float*)(smem + 131072);                   // [256]  (pre-GEMM only)
    float* tmp = h0s + 256;                                 // [512]
    float* gbf = h0s + 768;                                 // [256]

    const int tid  = threadIdx.x;
    const int lane = tid & 63;
    const int wid  = tid >> 6;
    const int fr = lane & 15;
    const int fq = lane >> 4;
    const int wm = (wid & 1) * 32;
    const int wn = (wid >> 1) * 64;
    const int m0 = blockIdx.x * 512;
    const int bb = blockIdx.x >> 2;     // 512-row span stays in one batch b

    // ---- chunk-0 A loads issued first; in flight through whole prologue ----
    float4 areg[8];
    {
        const float* aG = x + (size_t)(m0 + wid * 8) * I_SZ + lane * 4;
#pragma unroll
        for (int j = 0; j < 8; ++j) areg[j] = *(const float4*)(aG + j * I_SZ);
    }

    // ---- h0 stage ----
    if (tid < 256) h0s[tid] = h0[bb * H_SZ + tid];
    __syncthreads();

    // ---- gb partials: thread (h = tid&255, half = tid>>8) does 128 FMAs ----
    {
        const int h = tid & 255, half = tid >> 8;
        const float4* wr = (const float4*)(W_fh + (size_t)h * H_SZ + half * 128);
        const float* hv = h0s + half * 128;
        float a = 0.f;
#pragma unroll 8
        for (int j = 0; j < 32; ++j) {
            float4 w = wr[j];
            a = fmaf(w.x, hv[4 * j + 0], a);
            a = fmaf(w.y, hv[4 * j + 1], a);
            a = fmaf(w.z, hv[4 * j + 2], a);
            a = fmaf(w.w, hv[4 * j + 3], a);
        }
        tmp[h * 2 + half] = a;
    }
    __syncthreads();
    if (tid < 256) gbf[tid] = tmp[2 * tid] + tmp[2 * tid + 1] + b_fi[tid] + b_fh[tid];

    // ---- B stage: W_fi fp32 -> bf16, swizzled, whole 256x256 once ----
    {
        const int brow = tid >> 1, bhalf = tid & 1, brm = brow & 7;
        const float4* wG = (const float4*)(W_fi + (size_t)brow * I_SZ + bhalf * 128);
        unsigned short* bD = Bs + brow * 256;
#pragma unroll
        for (int g = 0; g < 16; ++g) {
            float4 u0 = wG[g * 2];
            float4 u1 = wG[g * 2 + 1];
            uint4 p;
            p.x = pack_bf16(u0.x, u0.y); p.y = pack_bf16(u0.z, u0.w);
            p.z = pack_bf16(u1.x, u1.y); p.w = pack_bf16(u1.z, u1.w);
            *(uint4*)(bD + (((bhalf * 16 + g) ^ brm) * 8)) = p;
        }
    }
    __syncthreads();

    // ---- per-thread gb/c0 into registers ----
    const int coln = wn + fr;
    float gbv[4], c0v[4];
#pragma unroll
    for (int ni = 0; ni < 4; ++ni) {
        gbv[ni] = gbf[coln + ni * 16];
        c0v[ni] = c0[bb * H_SZ + coln + ni * 16];
    }
    __syncthreads();   // gbf reads complete; As region free for overwrite

    // ---- staging helpers (A: 1 row per wave per instr, coalesced) ----
    auto WRITEA = [&]() {
#pragma unroll
        for (int j = 0; j < 8; ++j) {
            const int row = wid * 8 + j;
            uint2 p;
            p.x = pack_bf16(areg[j].x, areg[j].y);
            p.y = pack_bf16(areg[j].z, areg[j].w);
            *(uint2*)(As + row * 256 + (((lane >> 1) ^ (row & 7)) * 8 + (lane & 1) * 4)) = p;
        }
    };
    auto LOADA = [&](int c) {
        const float* aG = x + (size_t)(m0 + c * 64 + wid * 8) * I_SZ + lane * 4;
#pragma unroll
        for (int j = 0; j < 8; ++j) areg[j] = *(const float4*)(aG + j * I_SZ);
    };

    WRITEA();          // chunk 0
    LOADA(1);          // chunk 1 in flight across chunk-0 compute
    asm volatile("s_waitcnt lgkmcnt(0)" ::: "memory");
    __builtin_amdgcn_sched_barrier(0);
    __builtin_amdgcn_s_barrier();
    __builtin_amdgcn_sched_barrier(0);

    const int frm = fr & 7;
    const unsigned short* aB = As + (wm + fr) * 256;           // + mi*4096
    const unsigned short* bB[4];
#pragma unroll
    for (int ni = 0; ni < 4; ++ni) bB[ni] = Bs + (wn + ni * 16 + fr) * 256;

    for (int ch = 0; ch < 8; ++ch) {
        f32x4 acc[2][4];
#pragma unroll
        for (int mi = 0; mi < 2; ++mi)
#pragma unroll
            for (int ni = 0; ni < 4; ++ni)
                acc[mi][ni] = (f32x4){0.f, 0.f, 0.f, 0.f};

        // ---- K-loop: pure LDS + MFMA, barrier-free ----
        __builtin_amdgcn_s_setprio(1);
#pragma unroll
        for (int kt = 0; kt < 8; ++kt) {
            const int e = ((kt * 4 + fq) ^ frm) * 8;
            s16x8 af0 = *(const s16x8*)(aB + e);
            s16x8 af1 = *(const s16x8*)(aB + 4096 + e);
            s16x8 bf0 = *(const s16x8*)(bB[0] + e);
            s16x8 bf1 = *(const s16x8*)(bB[1] + e);
            s16x8 bf2 = *(const s16x8*)(bB[2] + e);
            s16x8 bf3 = *(const s16x8*)(bB[3] + e);
            acc[0][0] = __builtin_amdgcn_mfma_f32_16x16x32_bf16(af0, bf0, acc[0][0], 0, 0, 0);
            acc[0][1] = __builtin_amdgcn_mfma_f32_16x16x32_bf16(af0, bf1, acc[0][1], 0, 0, 0);
            acc[0][2] = __builtin_amdgcn_mfma_f32_16x16x32_bf16(af0, bf2, acc[0][2], 0, 0, 0);
            acc[0][3] = __builtin_amdgcn_mfma_f32_16x16x32_bf16(af0, bf3, acc[0][3], 0, 0, 0);
            acc[1][0] = __builtin_amdgcn_mfma_f32_16x16x32_bf16(af1, bf0, acc[1][0], 0, 0, 0);
            acc[1][1] = __builtin_amdgcn_mfma_f32_16x16x32_bf16(af1, bf1, acc[1][1], 0, 0, 0);
            acc[1][2] = __builtin_amdgcn_mfma_f32_16x16x32_bf16(af1, bf2, acc[1][2], 0, 0, 0);
            acc[1][3] = __builtin_amdgcn_mfma_f32_16x16x32_bf16(af1, bf3, acc[1][3], 0, 0, 0);
        }
        __builtin_amdgcn_s_setprio(0);

        // ---- fused LSTM epilogue for this chunk ----
        const int mrow = m0 + ch * 64 + wm;
#pragma unroll
        for (int mi = 0; mi < 2; ++mi) {
#pragma unroll
            for (int r = 0; r < 4; ++r) {
                const int Mg = mrow + mi * 16 + fq * 4 + r;
                const int tt = Mg & (T_SZ - 1);
                const int obase = tt * (B_SZ * H_SZ) + bb * H_SZ;
                const bool last = (tt == T_SZ - 1);
#pragma unroll
                for (int ni = 0; ni < 4; ++ni) {
                    const int h = coln + ni * 16;
                    float g = acc[mi][ni][r] + gbv[ni];
                    float gc = fmaxf(-15.f, g);                        // NaN guard
                    float e = __expf(-gc);
                    float s = __builtin_amdgcn_rcpf(1.f + e);          // sigmoid
                    float e2 = e * e;
                    float m = (1.f - e2) * __builtin_amdgcn_rcpf(1.f + e2);  // tanh(g)
                    float cv = s * (c0v[ni] + m);                      // |cv|<=|c0|+1
                    float ec = __expf(-2.f * cv);
                    float th = (1.f - ec) * __builtin_amdgcn_rcpf(1.f + ec); // tanh(c)
                    float hv = s * th;
                    out[obase + h] = hv;
                    if (last) {
                        out[TBH + bb * H_SZ + h] = hv;                  // h_last
                        out[TBH + B_SZ * H_SZ + bb * H_SZ + h] = cv;    // c_last
                    }
                }
            }
        }

        // ---- restage As for next chunk ----
        if (ch < 7) {
            __builtin_amdgcn_sched_barrier(0);
            __builtin_amdgcn_s_barrier();       // all waves done reading As(ch)
            __builtin_amdgcn_sched_barrier(0);
            WRITEA();                           // counted vmcnt on 1-chunk-old loads
            if (ch < 6) LOADA(ch + 2);
            asm volatile("s_waitcnt lgkmcnt(0)" ::: "memory");
            __builtin_amdgcn_sched_barrier(0);
            __builtin_amdgcn_s_barrier();
            __builtin_amdgcn_sched_barrier(0);
        }
    }
}

extern "C" void kernel_launch(void* const* d_in, const int* in_sizes, int n_in,
                              void* d_out, int out_size, void* d_ws, size_t ws_size,
                              hipStream_t stream) {
    const float* x    = (const float*)d_in[0];
    const float* h0   = (const float*)d_in[1];
    const float* c0   = (const float*)d_in[2];
    const float* W_fi = (const float*)d_in[3];
    const float* b_fi = (const float*)d_in[4];
    const float* W_fh = (const float*)d_in[5];
    const float* b_fh = (const float*)d_in[6];
    float* out = (float*)d_out;

    hipLaunchKernelGGL(lstm_fused, dim3(M_SZ / 512), dim3(512), 0, stream,
                       x, h0, c0, W_fi, b_fi, W_fh, b_fh, out);
}